// Round 1
// baseline (690.691 us; speedup 1.0000x reference)
//
#include <hip/hip_runtime.h>

#define N_NODES 100000
#define N_EDGES 3200000
#define N_FEAT 512
#define HIDDEN 16
#define N_CLASSES 40
#define NXCD 8

#define SCAN_BLOCKS 98   // ceil(100000/1024)

// ---------------- init / degree ----------------

__global__ void k_zero_int(int* p, int n) {
    int i = blockIdx.x * 256 + threadIdx.x;
    if (i < n) p[i] = 0;
}

// Which XCD is this workgroup on? (gfx950: 8 XCDs, id 0..7)
__device__ __forceinline__ int xcc_id() {
    int x;
    asm("s_getreg_b32 %0, hwreg(HW_REG_XCC_ID)" : "=s"(x));
    return x & (NXCD - 1);
}

// Count in-edges per dst into a PER-XCD private histogram copy.
// All atomics to copy c come from XCD c only -> workgroup-scope atomic
// (no sc1, executes in the XCD's own L2, copy is L2-resident: 400 KB).
// Device-scope atomics here were memory-side RMWs: 112 MB WRITE_SIZE,
// 150 us. ord[e] packs (local ordinal << 3) | xcd.
__global__ void k_count(const int* __restrict__ dst, int* __restrict__ cnt8,
                        int* __restrict__ ord) {
    int e = blockIdx.x * 256 + threadIdx.x;
    if (e >= N_EDGES) return;
    int c = xcc_id();            // wave-uniform SGPR
    int d = dst[e];
    int o = __hip_atomic_fetch_add(cnt8 + c * N_NODES + d, 1,
                                   __ATOMIC_RELAXED, __HIP_MEMORY_SCOPE_WORKGROUP);
    ord[e] = (o << 3) | c;
}

// Merge the 8 copies: per-node exclusive prefix across copies (in place),
// total count -> cnt, and dinv fused here (replaces k_dinv).
__global__ void k_merge(int* __restrict__ cnt8, int* __restrict__ cnt,
                        float* __restrict__ dinv) {
    int i = blockIdx.x * 256 + threadIdx.x;
    if (i >= N_NODES) return;
    int s = 0;
    #pragma unroll
    for (int c = 0; c < NXCD; c++) {
        int v = cnt8[c * N_NODES + i];
        cnt8[c * N_NODES + i] = s;   // exclusive offset of copy c within node i
        s += v;
    }
    cnt[i] = s;
    dinv[i] = rsqrtf((float)(s + 1));  // +1 self-loop
}

// ---------------- 3-phase exclusive scan of cnt -> row_start ----------------

__global__ __launch_bounds__(1024) void k_scan_a(const int* __restrict__ cnt,
                                                 int* __restrict__ bsum) {
    int tid = threadIdx.x;
    int i = blockIdx.x * 1024 + tid;
    int v = (i < N_NODES) ? cnt[i] : 0;
    #pragma unroll
    for (int off = 32; off >= 1; off >>= 1) v += __shfl_xor(v, off, 64);
    __shared__ int ws[16];
    if ((tid & 63) == 0) ws[tid >> 6] = v;
    __syncthreads();
    if (tid == 0) {
        int s = 0;
        #pragma unroll
        for (int w = 0; w < 16; w++) s += ws[w];
        bsum[blockIdx.x] = s;
    }
}

__global__ __launch_bounds__(128) void k_scan_b(const int* __restrict__ bsum,
                                                int* __restrict__ boff) {
    int tid = threadIdx.x;
    int lane = tid & 63, wv = tid >> 6;
    int v = (tid < SCAN_BLOCKS) ? bsum[tid] : 0;
    int sc = v;
    #pragma unroll
    for (int off = 1; off < 64; off <<= 1) {
        int t = __shfl_up(sc, off, 64);
        if (lane >= off) sc += t;
    }
    __shared__ int wsum[2];
    if (lane == 63) wsum[wv] = sc;
    __syncthreads();
    int pre = (wv == 1) ? wsum[0] : 0;
    if (tid < SCAN_BLOCKS) boff[tid] = pre + sc - v;  // exclusive
}

__global__ __launch_bounds__(1024) void k_scan_c(const int* __restrict__ cnt,
                                                 const int* __restrict__ boff,
                                                 int* __restrict__ row_start) {
    int tid = threadIdx.x;
    int i = blockIdx.x * 1024 + tid;
    int lane = tid & 63, wv = tid >> 6;
    int v = (i < N_NODES) ? cnt[i] : 0;
    int sc = v;
    #pragma unroll
    for (int off = 1; off < 64; off <<= 1) {
        int t = __shfl_up(sc, off, 64);
        if (lane >= off) sc += t;
    }
    __shared__ int wsum[16];
    if (lane == 63) wsum[wv] = sc;
    __syncthreads();
    int pre = 0;
    #pragma unroll
    for (int w = 0; w < 16; w++) pre += (w < wv) ? wsum[w] : 0;
    int excl = boff[blockIdx.x] + pre + sc - v;
    if (i < N_NODES) row_start[i] = excl;
    if (i == N_NODES) row_start[N_NODES] = N_EDGES;
}

// place each edge at row_start[dst] + copy_offset + local ord
__global__ void k_build(const int* __restrict__ src, const int* __restrict__ dst,
                        const int* __restrict__ ord, const int* __restrict__ row_start,
                        const int* __restrict__ cnt8, const float* __restrict__ dinv,
                        int2* __restrict__ edge_data) {
    int e = blockIdx.x * 256 + threadIdx.x;
    if (e >= N_EDGES) return;
    int s = src[e], d = dst[e];
    int oc = ord[e];
    int c = oc & (NXCD - 1), o = oc >> 3;
    int slot = row_start[d] + cnt8[c * N_NODES + d] + o;
    float nrm = dinv[s] * dinv[d];
    edge_data[slot] = make_int2(s, __float_as_int(nrm));
}

// ---------------- GEMM1: h1[N,16] = x[N,512] @ W1[512,16] ----------------
// 256 rows/block, thread owns one row. K chunked by 32, staged dense in LDS
// ([256][36] pad -> bank-balanced b128 reads/writes). W1 read at wave-uniform
// indices -> scalar-cache s_load, off the VMEM pipe.

#define KC 32
#define LDSW 36

__global__ __launch_bounds__(256) void k_gemm1(const float* __restrict__ x,
                                               const float* __restrict__ W1,
                                               float* __restrict__ h1) {
    __shared__ float xs[256 * LDSW];
    int tid = threadIdx.x;
    int row = blockIdx.x * 256 + tid;

    float acc[HIDDEN];
    #pragma unroll
    for (int j = 0; j < HIDDEN; j++) acc[j] = 0.f;

    int s_sub = tid >> 3;  // 0..31 staging row-sub
    int s_k4  = tid & 7;   // 0..7  staging k4

    for (int kc = 0; kc < N_FEAT; kc += KC) {
        __syncthreads();  // previous chunk's reads done before overwrite
        #pragma unroll
        for (int l = 0; l < 8; l++) {
            int srow = s_sub + l * 32;
            int grow = blockIdx.x * 256 + srow;
            int gr = grow < N_NODES ? grow : N_NODES - 1;  // clamp
            float4 v = *reinterpret_cast<const float4*>(
                x + (size_t)gr * N_FEAT + kc + s_k4 * 4);
            *reinterpret_cast<float4*>(&xs[srow * LDSW + s_k4 * 4]) = v;
        }
        __syncthreads();

        const float* Wc = W1 + kc * HIDDEN;  // wave-uniform
        #pragma unroll
        for (int k4 = 0; k4 < 8; k4++) {
            float4 xv = *reinterpret_cast<const float4*>(&xs[tid * LDSW + k4 * 4]);
            const float* w0 = Wc + (k4 * 4 + 0) * HIDDEN;
            const float* w1 = Wc + (k4 * 4 + 1) * HIDDEN;
            const float* w2 = Wc + (k4 * 4 + 2) * HIDDEN;
            const float* w3 = Wc + (k4 * 4 + 3) * HIDDEN;
            #pragma unroll
            for (int j = 0; j < HIDDEN; j++) {
                acc[j] += xv.x * w0[j];
                acc[j] += xv.y * w1[j];
                acc[j] += xv.z * w2[j];
                acc[j] += xv.w * w3[j];
            }
        }
    }

    if (row < N_NODES) {
        float4* op = reinterpret_cast<float4*>(h1 + (size_t)row * HIDDEN);
        #pragma unroll
        for (int q = 0; q < 4; q++)
            op[q] = make_float4(acc[q*4+0], acc[q*4+1], acc[q*4+2], acc[q*4+3]);
    }
}

// ---------------- CSR aggregation over 16 features ----------------
// 16 threads per node, 16 nodes/block. 4-wide edge unroll for MLP.

template <bool RELU>
__global__ __launch_bounds__(256) void k_agg16(const int2* __restrict__ edge_data,
                                               const int* __restrict__ row_start,
                                               const float* __restrict__ dinv,
                                               const float* __restrict__ h,
                                               const float* __restrict__ bias,
                                               float* __restrict__ out) {
    int g = threadIdx.x >> 4, j = threadIdx.x & 15;
    int node = blockIdx.x * 16 + g;
    if (node >= N_NODES) return;
    int beg = row_start[node], end = row_start[node + 1];
    float ds = dinv[node];
    float acc = h[(size_t)node * HIDDEN + j] * (ds * ds);  // self loop
    int i = beg;
    for (; i + 3 < end; i += 4) {
        int2 e0 = edge_data[i + 0];
        int2 e1 = edge_data[i + 1];
        int2 e2 = edge_data[i + 2];
        int2 e3 = edge_data[i + 3];
        float v0 = h[(size_t)e0.x * HIDDEN + j];
        float v1 = h[(size_t)e1.x * HIDDEN + j];
        float v2 = h[(size_t)e2.x * HIDDEN + j];
        float v3 = h[(size_t)e3.x * HIDDEN + j];
        acc += v0 * __int_as_float(e0.y);
        acc += v1 * __int_as_float(e1.y);
        acc += v2 * __int_as_float(e2.y);
        acc += v3 * __int_as_float(e3.y);
    }
    for (; i < end; ++i) {
        int2 ed = edge_data[i];
        acc += h[(size_t)ed.x * HIDDEN + j] * __int_as_float(ed.y);
    }
    if (RELU) acc = fmaxf(acc + bias[j], 0.f);
    out[(size_t)node * HIDDEN + j] = acc;
}

// ---------------- final: out = agg2 @ W2 + b2, log_softmax ----------------

__global__ __launch_bounds__(256) void k_out(const float* __restrict__ agg2,
                                             const float* __restrict__ W2,
                                             const float* __restrict__ b2,
                                             float* __restrict__ out) {
    int r = blockIdx.x * 256 + threadIdx.x;
    if (r >= N_NODES) return;
    float a[HIDDEN];
    const float4* ap = reinterpret_cast<const float4*>(agg2 + (size_t)r * HIDDEN);
    #pragma unroll
    for (int q = 0; q < 4; q++) {
        float4 v = ap[q];
        a[q * 4 + 0] = v.x; a[q * 4 + 1] = v.y;
        a[q * 4 + 2] = v.z; a[q * 4 + 3] = v.w;
    }
    float acc[N_CLASSES];
    #pragma unroll
    for (int jj = 0; jj < N_CLASSES; jj++) acc[jj] = b2[jj];
    #pragma unroll
    for (int kk = 0; kk < HIDDEN; kk++) {
        float av = a[kk];
        #pragma unroll
        for (int jj = 0; jj < N_CLASSES; jj++)
            acc[jj] += av * W2[kk * N_CLASSES + jj];  // uniform -> scalar loads
    }
    float m = -1e30f;
    #pragma unroll
    for (int jj = 0; jj < N_CLASSES; jj++) m = fmaxf(m, acc[jj]);
    float sum = 0.f;
    #pragma unroll
    for (int jj = 0; jj < N_CLASSES; jj++) sum += __expf(acc[jj] - m);
    float l = m + __logf(sum);
    float4* op = reinterpret_cast<float4*>(out + (size_t)r * N_CLASSES);
    #pragma unroll
    for (int q = 0; q < N_CLASSES / 4; q++) {
        op[q] = make_float4(acc[q*4+0] - l, acc[q*4+1] - l,
                            acc[q*4+2] - l, acc[q*4+3] - l);
    }
}

// ---------------- launch ----------------

extern "C" void kernel_launch(void* const* d_in, const int* in_sizes, int n_in,
                              void* d_out, int out_size, void* d_ws, size_t ws_size,
                              hipStream_t stream) {
    const float* x  = (const float*)d_in[0];
    const int*   ei = (const int*)d_in[1];   // int64 ref -> int32 in harness
    const float* W1 = (const float*)d_in[2];
    const float* b1 = (const float*)d_in[3];
    const float* W2 = (const float*)d_in[4];
    const float* b2 = (const float*)d_in[5];
    const int* src = ei;
    const int* dst = ei + N_EDGES;
    float* out = (float*)d_out;

    // workspace layout (256B-aligned)
    char* ws = (char*)d_ws;
    size_t off = 0;
    auto alloc = [&](size_t bytes) {
        size_t o = off; off = (off + bytes + 255) & ~(size_t)255; return o;
    };
    float* dinv      = (float*)(ws + alloc(sizeof(float) * N_NODES));
    int*   cnt       = (int*)  (ws + alloc(sizeof(int) * N_NODES));
    int*   row_start = (int*)  (ws + alloc(sizeof(int) * (N_NODES + 1)));
    int*   ord       = (int*)  (ws + alloc(sizeof(int) * N_EDGES));
    int2*  edge_data = (int2*) (ws + alloc(sizeof(int2) * N_EDGES));
    float* h1        = (float*)(ws + alloc(sizeof(float) * N_NODES * HIDDEN));
    float* rbuf      = (float*)(ws + alloc(sizeof(float) * N_NODES * HIDDEN));
    float* agg2      = (float*)(ws + alloc(sizeof(float) * N_NODES * HIDDEN));
    int*   bsum      = (int*)  (ws + alloc(sizeof(int) * SCAN_BLOCKS));
    int*   boff      = (int*)  (ws + alloc(sizeof(int) * SCAN_BLOCKS));
    // per-XCD histogram copies (3.2 MB); alias agg2's space — agg2 is first
    // written by the second k_agg16, strictly after k_build's last cnt8 read.
    int*   cnt8      = (int*)agg2;

    const int nodeBlocks  = (N_NODES + 255) / 256;          // 391
    const int edgeBlocks  = (N_EDGES + 255) / 256;          // 12500
    const int aggBlocks   = (N_NODES + 15) / 16;            // 6250
    const int zero8Blocks = (NXCD * N_NODES + 255) / 256;   // 3125

    k_zero_int<<<zero8Blocks, 256, 0, stream>>>(cnt8, NXCD * N_NODES);
    k_count<<<edgeBlocks, 256, 0, stream>>>(dst, cnt8, ord);
    k_merge<<<nodeBlocks, 256, 0, stream>>>(cnt8, cnt, dinv);
    k_scan_a<<<SCAN_BLOCKS, 1024, 0, stream>>>(cnt, bsum);
    k_scan_b<<<1, 128, 0, stream>>>(bsum, boff);
    k_scan_c<<<SCAN_BLOCKS, 1024, 0, stream>>>(cnt, boff, row_start);
    k_build<<<edgeBlocks, 256, 0, stream>>>(src, dst, ord, row_start, cnt8, dinv, edge_data);

    k_gemm1<<<nodeBlocks, 256, 0, stream>>>(x, W1, h1);
    k_agg16<true><<<aggBlocks, 256, 0, stream>>>(edge_data, row_start, dinv, h1, b1, rbuf);
    k_agg16<false><<<aggBlocks, 256, 0, stream>>>(edge_data, row_start, dinv, rbuf, nullptr, agg2);
    k_out<<<nodeBlocks, 256, 0, stream>>>(agg2, W2, b2, out);
}

// Round 2
// 621.066 us; speedup vs baseline: 1.1121x; 1.1121x over previous
//
#include <hip/hip_runtime.h>

#define N_NODES 100000
#define N_EDGES 3200000
#define N_FEAT 512
#define HIDDEN 16
#define N_CLASSES 40

#define SCAN_BLOCKS 98   // ceil(100000/1024)

// ---- chunked counting-sort CSR build ----
// CH nodes per chunk (64 KB LDS histogram), NCH chunks, NS edge slices.
#define CH    16384
#define NCH   7                    // ceil(100000/16384)
#define NS    32
#define SLICE (N_EDGES / NS)       // 100000 edges per slice (exact)
#define SL4   (SLICE / 4)          // int4 loads per slice (exact)

// Pass 1: per-(chunk, slice) partial histogram via LDS atomics.
// partS[s][n] (slice-major) -> all global writes coalesced. No global atomics.
__global__ __launch_bounds__(512) void k_p1(const int* __restrict__ dst,
                                            int* __restrict__ partS) {
    __shared__ int hist[CH];
    int tid = threadIdx.x;
    int s = blockIdx.x, j = blockIdx.y;
    int base = j * CH;
    int lim = N_NODES - base; if (lim > CH) lim = CH;
    for (int i = tid; i < CH; i += 512) hist[i] = 0;
    __syncthreads();
    const int4* dp = reinterpret_cast<const int4*>(dst + s * SLICE);
    for (int i = tid; i < SL4; i += 512) {
        int4 d4 = dp[i];
        unsigned a = (unsigned)(d4.x - base); if (a < (unsigned)lim) atomicAdd(&hist[a], 1);
        unsigned b = (unsigned)(d4.y - base); if (b < (unsigned)lim) atomicAdd(&hist[b], 1);
        unsigned c = (unsigned)(d4.z - base); if (c < (unsigned)lim) atomicAdd(&hist[c], 1);
        unsigned d = (unsigned)(d4.w - base); if (d < (unsigned)lim) atomicAdd(&hist[d], 1);
    }
    __syncthreads();
    for (int i = tid; i < lim; i += 512)
        partS[s * N_NODES + base + i] = hist[i];
}

// Per-node exclusive scan across the 32 slices (in place, coalesced per slice
// step), total degree -> deg, dinv fused.
__global__ __launch_bounds__(256) void k_colscan(int* __restrict__ partS,
                                                 int* __restrict__ deg,
                                                 float* __restrict__ dinv) {
    int n = blockIdx.x * 256 + threadIdx.x;
    if (n >= N_NODES) return;
    int run = 0;
    #pragma unroll
    for (int s = 0; s < NS; s++) {
        int idx = s * N_NODES + n;
        int v = partS[idx];
        partS[idx] = run;       // exclusive-over-slices within node n
        run += v;
    }
    deg[n] = run;
    dinv[n] = rsqrtf((float)(run + 1));  // +1 self-loop
}

// ---------------- 3-phase exclusive scan of deg -> row_start ----------------

__global__ __launch_bounds__(1024) void k_scan_a(const int* __restrict__ cnt,
                                                 int* __restrict__ bsum) {
    int tid = threadIdx.x;
    int i = blockIdx.x * 1024 + tid;
    int v = (i < N_NODES) ? cnt[i] : 0;
    #pragma unroll
    for (int off = 32; off >= 1; off >>= 1) v += __shfl_xor(v, off, 64);
    __shared__ int ws[16];
    if ((tid & 63) == 0) ws[tid >> 6] = v;
    __syncthreads();
    if (tid == 0) {
        int s = 0;
        #pragma unroll
        for (int w = 0; w < 16; w++) s += ws[w];
        bsum[blockIdx.x] = s;
    }
}

__global__ __launch_bounds__(128) void k_scan_b(const int* __restrict__ bsum,
                                                int* __restrict__ boff) {
    int tid = threadIdx.x;
    int lane = tid & 63, wv = tid >> 6;
    int v = (tid < SCAN_BLOCKS) ? bsum[tid] : 0;
    int sc = v;
    #pragma unroll
    for (int off = 1; off < 64; off <<= 1) {
        int t = __shfl_up(sc, off, 64);
        if (lane >= off) sc += t;
    }
    __shared__ int wsum[2];
    if (lane == 63) wsum[wv] = sc;
    __syncthreads();
    int pre = (wv == 1) ? wsum[0] : 0;
    if (tid < SCAN_BLOCKS) boff[tid] = pre + sc - v;  // exclusive
}

__global__ __launch_bounds__(1024) void k_scan_c(const int* __restrict__ cnt,
                                                 const int* __restrict__ boff,
                                                 int* __restrict__ row_start) {
    int tid = threadIdx.x;
    int i = blockIdx.x * 1024 + tid;
    int lane = tid & 63, wv = tid >> 6;
    int v = (i < N_NODES) ? cnt[i] : 0;
    int sc = v;
    #pragma unroll
    for (int off = 1; off < 64; off <<= 1) {
        int t = __shfl_up(sc, off, 64);
        if (lane >= off) sc += t;
    }
    __shared__ int wsum[16];
    if (lane == 63) wsum[wv] = sc;
    __syncthreads();
    int pre = 0;
    #pragma unroll
    for (int w = 0; w < 16; w++) pre += (w < wv) ? wsum[w] : 0;
    int excl = boff[blockIdx.x] + pre + sc - v;
    if (i < N_NODES) row_start[i] = excl;
    if (i == N_NODES) row_start[N_NODES] = N_EDGES;
}

// Pass 2: re-stream slice, LDS cursor = row_start + partS (global slot base
// for this (node, slice)); returning LDS atomic gives each edge a unique
// slot. Fuses the old k_build (writes edge_data = {src, norm} directly).
__global__ __launch_bounds__(512) void k_p2(const int* __restrict__ src,
                                            const int* __restrict__ dst,
                                            const int* __restrict__ partS,
                                            const int* __restrict__ row_start,
                                            const float* __restrict__ dinv,
                                            int2* __restrict__ edge_data) {
    __shared__ int cur[CH];
    int tid = threadIdx.x;
    int s = blockIdx.x, j = blockIdx.y;
    int base = j * CH;
    int lim = N_NODES - base; if (lim > CH) lim = CH;
    for (int i = tid; i < lim; i += 512)
        cur[i] = row_start[base + i] + partS[s * N_NODES + base + i];
    __syncthreads();
    const int4* dp = reinterpret_cast<const int4*>(dst + s * SLICE);
    const int4* sp = reinterpret_cast<const int4*>(src + s * SLICE);
    for (int i = tid; i < SL4; i += 512) {
        int4 d4 = dp[i];
        int4 s4 = sp[i];
        {
            unsigned nl = (unsigned)(d4.x - base);
            if (nl < (unsigned)lim) {
                int slot = atomicAdd(&cur[nl], 1);
                edge_data[slot] = make_int2(s4.x, __float_as_int(dinv[s4.x] * dinv[d4.x]));
            }
        }
        {
            unsigned nl = (unsigned)(d4.y - base);
            if (nl < (unsigned)lim) {
                int slot = atomicAdd(&cur[nl], 1);
                edge_data[slot] = make_int2(s4.y, __float_as_int(dinv[s4.y] * dinv[d4.y]));
            }
        }
        {
            unsigned nl = (unsigned)(d4.z - base);
            if (nl < (unsigned)lim) {
                int slot = atomicAdd(&cur[nl], 1);
                edge_data[slot] = make_int2(s4.z, __float_as_int(dinv[s4.z] * dinv[d4.z]));
            }
        }
        {
            unsigned nl = (unsigned)(d4.w - base);
            if (nl < (unsigned)lim) {
                int slot = atomicAdd(&cur[nl], 1);
                edge_data[slot] = make_int2(s4.w, __float_as_int(dinv[s4.w] * dinv[d4.w]));
            }
        }
    }
}

// ---------------- GEMM1: h1[N,16] = x[N,512] @ W1[512,16] ----------------
// 256 rows/block, thread owns one row. K chunked by 32, staged dense in LDS
// ([256][36] pad -> bank-balanced b128 reads/writes). W1 read at wave-uniform
// indices -> scalar-cache s_load, off the VMEM pipe.

#define KC 32
#define LDSW 36

__global__ __launch_bounds__(256) void k_gemm1(const float* __restrict__ x,
                                               const float* __restrict__ W1,
                                               float* __restrict__ h1) {
    __shared__ float xs[256 * LDSW];
    int tid = threadIdx.x;
    int row = blockIdx.x * 256 + tid;

    float acc[HIDDEN];
    #pragma unroll
    for (int j = 0; j < HIDDEN; j++) acc[j] = 0.f;

    int s_sub = tid >> 3;  // 0..31 staging row-sub
    int s_k4  = tid & 7;   // 0..7  staging k4

    for (int kc = 0; kc < N_FEAT; kc += KC) {
        __syncthreads();  // previous chunk's reads done before overwrite
        #pragma unroll
        for (int l = 0; l < 8; l++) {
            int srow = s_sub + l * 32;
            int grow = blockIdx.x * 256 + srow;
            int gr = grow < N_NODES ? grow : N_NODES - 1;  // clamp
            float4 v = *reinterpret_cast<const float4*>(
                x + (size_t)gr * N_FEAT + kc + s_k4 * 4);
            *reinterpret_cast<float4*>(&xs[srow * LDSW + s_k4 * 4]) = v;
        }
        __syncthreads();

        const float* Wc = W1 + kc * HIDDEN;  // wave-uniform
        #pragma unroll
        for (int k4 = 0; k4 < 8; k4++) {
            float4 xv = *reinterpret_cast<const float4*>(&xs[tid * LDSW + k4 * 4]);
            const float* w0 = Wc + (k4 * 4 + 0) * HIDDEN;
            const float* w1 = Wc + (k4 * 4 + 1) * HIDDEN;
            const float* w2 = Wc + (k4 * 4 + 2) * HIDDEN;
            const float* w3 = Wc + (k4 * 4 + 3) * HIDDEN;
            #pragma unroll
            for (int j = 0; j < HIDDEN; j++) {
                acc[j] += xv.x * w0[j];
                acc[j] += xv.y * w1[j];
                acc[j] += xv.z * w2[j];
                acc[j] += xv.w * w3[j];
            }
        }
    }

    if (row < N_NODES) {
        float4* op = reinterpret_cast<float4*>(h1 + (size_t)row * HIDDEN);
        #pragma unroll
        for (int q = 0; q < 4; q++)
            op[q] = make_float4(acc[q*4+0], acc[q*4+1], acc[q*4+2], acc[q*4+3]);
    }
}

// ---------------- CSR aggregation over 16 features ----------------
// 16 threads per node, 16 nodes/block. 4-wide edge unroll for MLP.

template <bool RELU>
__global__ __launch_bounds__(256) void k_agg16(const int2* __restrict__ edge_data,
                                               const int* __restrict__ row_start,
                                               const float* __restrict__ dinv,
                                               const float* __restrict__ h,
                                               const float* __restrict__ bias,
                                               float* __restrict__ out) {
    int g = threadIdx.x >> 4, j = threadIdx.x & 15;
    int node = blockIdx.x * 16 + g;
    if (node >= N_NODES) return;
    int beg = row_start[node], end = row_start[node + 1];
    float ds = dinv[node];
    float acc = h[(size_t)node * HIDDEN + j] * (ds * ds);  // self loop
    int i = beg;
    for (; i + 3 < end; i += 4) {
        int2 e0 = edge_data[i + 0];
        int2 e1 = edge_data[i + 1];
        int2 e2 = edge_data[i + 2];
        int2 e3 = edge_data[i + 3];
        float v0 = h[(size_t)e0.x * HIDDEN + j];
        float v1 = h[(size_t)e1.x * HIDDEN + j];
        float v2 = h[(size_t)e2.x * HIDDEN + j];
        float v3 = h[(size_t)e3.x * HIDDEN + j];
        acc += v0 * __int_as_float(e0.y);
        acc += v1 * __int_as_float(e1.y);
        acc += v2 * __int_as_float(e2.y);
        acc += v3 * __int_as_float(e3.y);
    }
    for (; i < end; ++i) {
        int2 ed = edge_data[i];
        acc += h[(size_t)ed.x * HIDDEN + j] * __int_as_float(ed.y);
    }
    if (RELU) acc = fmaxf(acc + bias[j], 0.f);
    out[(size_t)node * HIDDEN + j] = acc;
}

// ---------------- final: out = agg2 @ W2 + b2, log_softmax ----------------

__global__ __launch_bounds__(256) void k_out(const float* __restrict__ agg2,
                                             const float* __restrict__ W2,
                                             const float* __restrict__ b2,
                                             float* __restrict__ out) {
    int r = blockIdx.x * 256 + threadIdx.x;
    if (r >= N_NODES) return;
    float a[HIDDEN];
    const float4* ap = reinterpret_cast<const float4*>(agg2 + (size_t)r * HIDDEN);
    #pragma unroll
    for (int q = 0; q < 4; q++) {
        float4 v = ap[q];
        a[q * 4 + 0] = v.x; a[q * 4 + 1] = v.y;
        a[q * 4 + 2] = v.z; a[q * 4 + 3] = v.w;
    }
    float acc[N_CLASSES];
    #pragma unroll
    for (int jj = 0; jj < N_CLASSES; jj++) acc[jj] = b2[jj];
    #pragma unroll
    for (int kk = 0; kk < HIDDEN; kk++) {
        float av = a[kk];
        #pragma unroll
        for (int jj = 0; jj < N_CLASSES; jj++)
            acc[jj] += av * W2[kk * N_CLASSES + jj];  // uniform -> scalar loads
    }
    float m = -1e30f;
    #pragma unroll
    for (int jj = 0; jj < N_CLASSES; jj++) m = fmaxf(m, acc[jj]);
    float sum = 0.f;
    #pragma unroll
    for (int jj = 0; jj < N_CLASSES; jj++) sum += __expf(acc[jj] - m);
    float l = m + __logf(sum);
    float4* op = reinterpret_cast<float4*>(out + (size_t)r * N_CLASSES);
    #pragma unroll
    for (int q = 0; q < N_CLASSES / 4; q++) {
        op[q] = make_float4(acc[q*4+0] - l, acc[q*4+1] - l,
                            acc[q*4+2] - l, acc[q*4+3] - l);
    }
}

// ---------------- launch ----------------

extern "C" void kernel_launch(void* const* d_in, const int* in_sizes, int n_in,
                              void* d_out, int out_size, void* d_ws, size_t ws_size,
                              hipStream_t stream) {
    const float* x  = (const float*)d_in[0];
    const int*   ei = (const int*)d_in[1];   // int64 ref -> int32 in harness
    const float* W1 = (const float*)d_in[2];
    const float* b1 = (const float*)d_in[3];
    const float* W2 = (const float*)d_in[4];
    const float* b2 = (const float*)d_in[5];
    const int* src = ei;
    const int* dst = ei + N_EDGES;
    float* out = (float*)d_out;

    // workspace layout (256B-aligned, ~59 MB total)
    char* ws = (char*)d_ws;
    size_t off = 0;
    auto alloc = [&](size_t bytes) {
        size_t o = off; off = (off + bytes + 255) & ~(size_t)255; return o;
    };
    float* dinv      = (float*)(ws + alloc(sizeof(float) * N_NODES));
    int*   cnt       = (int*)  (ws + alloc(sizeof(int) * N_NODES));
    int*   row_start = (int*)  (ws + alloc(sizeof(int) * (N_NODES + 1)));
    int*   partS     = (int*)  (ws + alloc(sizeof(int) * (size_t)NS * N_NODES));
    int2*  edge_data = (int2*) (ws + alloc(sizeof(int2) * N_EDGES));
    float* h1        = (float*)(ws + alloc(sizeof(float) * N_NODES * HIDDEN));
    float* rbuf      = (float*)(ws + alloc(sizeof(float) * N_NODES * HIDDEN));
    float* agg2      = (float*)(ws + alloc(sizeof(float) * N_NODES * HIDDEN));
    int*   bsum      = (int*)  (ws + alloc(sizeof(int) * SCAN_BLOCKS));
    int*   boff      = (int*)  (ws + alloc(sizeof(int) * SCAN_BLOCKS));

    const int nodeBlocks  = (N_NODES + 255) / 256;   // 391
    const int aggBlocks   = (N_NODES + 15) / 16;     // 6250
    dim3 csGrid(NS, NCH);                            // 32 x 7 = 224 WGs

    k_p1<<<csGrid, 512, 0, stream>>>(dst, partS);
    k_colscan<<<nodeBlocks, 256, 0, stream>>>(partS, cnt, dinv);
    k_scan_a<<<SCAN_BLOCKS, 1024, 0, stream>>>(cnt, bsum);
    k_scan_b<<<1, 128, 0, stream>>>(bsum, boff);
    k_scan_c<<<SCAN_BLOCKS, 1024, 0, stream>>>(cnt, boff, row_start);
    k_p2<<<csGrid, 512, 0, stream>>>(src, dst, partS, row_start, dinv, edge_data);

    k_gemm1<<<nodeBlocks, 256, 0, stream>>>(x, W1, h1);
    k_agg16<true><<<aggBlocks, 256, 0, stream>>>(edge_data, row_start, dinv, h1, b1, rbuf);
    k_agg16<false><<<aggBlocks, 256, 0, stream>>>(edge_data, row_start, dinv, rbuf, nullptr, agg2);
    k_out<<<nodeBlocks, 256, 0, stream>>>(agg2, W2, b2, out);
}